// Round 4
// baseline (69.400 us; speedup 1.0000x reference)
//
#include <hip/hip_runtime.h>

#define Bq 2
#define Nq 1024
#define Cq 128
#define Eq 64
#define Kq 20
#define TI 8
#define BNK (Bq * Nq * Kq)
#define NEGF (-3.0e38f)

// DPP shuffles (VALU pipe, no LDS): quad_perm xor1/xor2, row_ror 4/8
#define DPP_F(x, ctrl) __int_as_float(__builtin_amdgcn_update_dpp( \
    __float_as_int(x), __float_as_int(x), (ctrl), 0xf, 0xf, false))
#define DPP_I(x, ctrl) __builtin_amdgcn_update_dpp((x), (x), (ctrl), 0xf, 0xf, false)
#define RL_F(x, l) __int_as_float(__builtin_amdgcn_readlane(__float_as_int(x), (l)))
#define RL_I(x, l) __builtin_amdgcn_readlane((x), (l))
#define QP_XOR1 0xB1   // quad_perm [1,0,3,2]
#define QP_XOR2 0x4E   // quad_perm [2,3,0,1]
#define ROR4    0x124  // row_ror:4
#define ROR8    0x128  // row_ror:8

// ---------------- Kernel A: projections + rdot; x via scalar loads ----------------
// grid = (B*N)/4 blocks, block = 128. Lanes 0..63 (wave 0) -> Wl, 64..127 -> Wr.
__global__ __launch_bounds__(128) void proj_kernel(
    const float* __restrict__ x, const float* __restrict__ Wl,
    const float* __restrict__ bl, const float* __restrict__ Wr,
    const float* __restrict__ br, const float* __restrict__ att,
    float* __restrict__ xl, float* __restrict__ xrT, float* __restrict__ rdot) {
  const int r0 = blockIdx.x * 4;           // 4 rows per block
  const int t = threadIdx.x;
  const int e = t & 63;
  const bool left = (t < 64);
  const float* __restrict__ W = left ? Wl : Wr;
  const float* __restrict__ xrow = x + (size_t)r0 * Cq;  // block-uniform -> s_load

  float acc[4] = {0.f, 0.f, 0.f, 0.f};
#pragma unroll 8
  for (int c4 = 0; c4 < Cq / 4; ++c4) {
    const float4 xa = *(const float4*)&xrow[c4 * 4];
    const float4 xb = *(const float4*)&xrow[Cq + c4 * 4];
    const float4 xc = *(const float4*)&xrow[2 * Cq + c4 * 4];
    const float4 xd = *(const float4*)&xrow[3 * Cq + c4 * 4];
    const float a0[4] = {xa.x, xa.y, xa.z, xa.w};
    const float a1[4] = {xb.x, xb.y, xb.z, xb.w};
    const float a2[4] = {xc.x, xc.y, xc.z, xc.w};
    const float a3[4] = {xd.x, xd.y, xd.z, xd.w};
#pragma unroll
    for (int dd = 0; dd < 4; ++dd) {
      const float w = W[(c4 * 4 + dd) * Eq + e];
      acc[0] = fmaf(a0[dd], w, acc[0]);
      acc[1] = fmaf(a1[dd], w, acc[1]);
      acc[2] = fmaf(a2[dd], w, acc[2]);
      acc[3] = fmaf(a3[dd], w, acc[3]);
    }
  }
  const float bias = left ? bl[e] : br[e];
#pragma unroll
  for (int k = 0; k < 4; ++k) acc[k] += bias;

  if (left) {
#pragma unroll
    for (int k = 0; k < 4; ++k) xl[(size_t)(r0 + k) * Eq + e] = acc[k];
  } else {
    const float ae = att[e];
#pragma unroll
    for (int k = 0; k < 4; ++k) {
      xrT[(size_t)e * (Bq * Nq) + r0 + k] = acc[k];
      float s = acc[k] * ae;                     // rdot[row] = sum_e xr*att
      s += DPP_F(s, QP_XOR1);
      s += DPP_F(s, QP_XOR2);
      s += DPP_F(s, ROR4);
      s += DPP_F(s, ROR8);
      const float sd = (RL_F(s, 0) + RL_F(s, 16)) + (RL_F(s, 32) + RL_F(s, 48));
      if (e == 0) rdot[r0 + k] = sd;
    }
  }
}

// ---------------- Kernel B: scores (8 rows/block) + DPP top-K + softmax ----------------
// block = 512 (8 waves). Phase 1: thread = (rgroup of 4 rows) x (4 consecutive j).
// Phase 2: wave w owns row w; all cross-lane via DPP/readlane, zero LDS shuffles.
__global__ __launch_bounds__(512) void attn_kernel(
    const float* __restrict__ xl, const float* __restrict__ xrT,
    const float* __restrict__ rdot, const float* __restrict__ att,
    float* __restrict__ out) {
  const int gi0  = blockIdx.x * TI;
  const int b    = gi0 >> 10;
  const int tid  = threadIdx.x;
  const int lane = tid & 63;
  const int wave = tid >> 6;

  __shared__ float alpha[TI][Nq];   // 32 KB
  __shared__ float xls[TI][Eq];     // 2 KB

  xls[tid >> 6][tid & 63] = xl[(size_t)gi0 * Eq + tid];
  __syncthreads();

  // ---- phase 1: alphaS[r][j] = 1.5*rdot[j] + sum_d att[d]*|xl[r][d]+xr[j][d]| ----
  {
    const int jt = tid & 255;        // 256 j-threads
    const int j0 = jt * 4;
    const int rg = tid >> 8;         // 0/1 -> rows rg*4 .. rg*4+3
    const float4 rd4 = *(const float4*)&rdot[b * Nq + j0];
    const float rdv[4] = {rd4.x, rd4.y, rd4.z, rd4.w};
    float acc[4][4];
#pragma unroll
    for (int rr = 0; rr < 4; ++rr)
#pragma unroll
      for (int jj = 0; jj < 4; ++jj) acc[rr][jj] = 1.5f * rdv[jj];

    const float* __restrict__ xrb = xrT + (size_t)b * Nq + j0;
    for (int ch = 0; ch < 16; ++ch) {
      const float4 av4 = *(const float4*)&att[ch * 4];   // uniform -> s_load
      const float av[4] = {av4.x, av4.y, av4.z, av4.w};
      float xlr[4][4];
#pragma unroll
      for (int rr = 0; rr < 4; ++rr) {
        const float4 v = *(const float4*)&xls[rg * 4 + rr][ch * 4];  // broadcast
        xlr[rr][0] = v.x; xlr[rr][1] = v.y; xlr[rr][2] = v.z; xlr[rr][3] = v.w;
      }
#pragma unroll
      for (int dd = 0; dd < 4; ++dd) {
        const float4 xv4 = *(const float4*)&xrb[(size_t)(ch * 4 + dd) * (Bq * Nq)];
        const float xv[4] = {xv4.x, xv4.y, xv4.z, xv4.w};
        const float a = av[dd];
#pragma unroll
        for (int rr = 0; rr < 4; ++rr) {
          const float xld = xlr[rr][dd];
#pragma unroll
          for (int jj = 0; jj < 4; ++jj)
            acc[rr][jj] = fmaf(fabsf(xld + xv[jj]), a, acc[rr][jj]);
        }
      }
    }
#pragma unroll
    for (int rr = 0; rr < 4; ++rr)
      *(float4*)&alpha[rg * 4 + rr][j0] =
          make_float4(acc[rr][0], acc[rr][1], acc[rr][2], acc[rr][3]);
  }
  __syncthreads();

  // ---- phase 2: wave w = top-K of row w (j = lane + 64*s), DPP-only reduces ----
  float vals[16];
#pragma unroll
  for (int s = 0; s < 16; ++s) vals[s] = alpha[wave][lane + 64 * s];

  float lv = vals[0];
  int   pk = lane;                      // pk = (s<<6)|lane == j; min pk = min j
#pragma unroll
  for (int s = 1; s < 16; ++s)
    if (vals[s] > lv) { lv = vals[s]; pk = (s << 6) | lane; }

  float m0 = 0.f, ssum = 0.f, myv = 0.f;
  int myi = 0;
#pragma unroll 1
  for (int round = 0; round < Kq; ++round) {
    // 64-lane max of lv -> bv (uniform)
    float m = lv;
    m = fmaxf(m, DPP_F(m, QP_XOR1));
    m = fmaxf(m, DPP_F(m, QP_XOR2));
    m = fmaxf(m, DPP_F(m, ROR4));
    m = fmaxf(m, DPP_F(m, ROR8));
    const float bv = fmaxf(fmaxf(RL_F(m, 0), RL_F(m, 16)),
                           fmaxf(RL_F(m, 32), RL_F(m, 48)));
    // min-j among lanes holding bv (exact lax.top_k tie-break)
    int key = (lv == bv) ? pk : 0x7FFFFFFF;
    key = min(key, DPP_I(key, QP_XOR1));
    key = min(key, DPP_I(key, QP_XOR2));
    key = min(key, DPP_I(key, ROR4));
    key = min(key, DPP_I(key, ROR8));
    const int jsel = min(min(RL_I(key, 0), RL_I(key, 16)),
                         min(RL_I(key, 32), RL_I(key, 48)));
    if (round == 0) m0 = bv;
    ssum += __expf(0.4f * (bv - m0));   // undo the /0.4 scaling here
    if (lane == round) { myv = bv; myi = jsel; }
    // knockout + owner-lane rescan
    if (lane == (jsel & 63)) {
      const int sk = jsel >> 6;
#pragma unroll
      for (int s = 0; s < 16; ++s)
        if (s == sk) vals[s] = NEGF;
      lv = vals[0]; pk = lane;
#pragma unroll
      for (int s = 1; s < 16; ++s)
        if (vals[s] > lv) { lv = vals[s]; pk = (s << 6) | lane; }
    }
  }

  if (lane < Kq) {
    const int gi = gi0 + wave;
    const float p = __expf(0.4f * (myv - m0)) / ssum;
    const int base = gi * Kq + lane;
    out[base]            = (float)gi;              // index_i
    out[BNK + base]      = (float)(b * Nq + myi);  // index_j
    out[2 * BNK + base]  = p;                      // attention
  }
}

extern "C" void kernel_launch(void* const* d_in, const int* in_sizes, int n_in,
                              void* d_out, int out_size, void* d_ws, size_t ws_size,
                              hipStream_t stream) {
  const float* x   = (const float*)d_in[0];
  const float* Wl  = (const float*)d_in[1];
  const float* bl  = (const float*)d_in[2];
  const float* Wr  = (const float*)d_in[3];
  const float* br  = (const float*)d_in[4];
  const float* att = (const float*)d_in[5];
  float* out = (float*)d_out;

  float* xl   = (float*)d_ws;                    // [B*N, E]
  float* xrT  = xl + (size_t)Bq * Nq * Eq;       // [E, B*N]
  float* rdot = xrT + (size_t)Eq * Bq * Nq;      // [B*N]

  proj_kernel<<<(Bq * Nq) / 4, 128, 0, stream>>>(x, Wl, bl, Wr, br, att, xl, xrT, rdot);
  // PROBE (this round only): launch attn twice. The second launch re-reads the
  // identical ws state and rewrites the identical output (deterministic,
  // graph-safe). Delta dur_us vs R3 == one attn_kernel duration, measured
  // without rocprof overhead — discriminates "39us harness floor" vs
  // "attn is actually ~35us".
  attn_kernel<<<(Bq * Nq) / TI, 512, 0, stream>>>(xl, xrT, rdot, att, out);
  attn_kernel<<<(Bq * Nq) / TI, 512, 0, stream>>>(xl, xrT, rdot, att, out);
}

// Round 5
// 41.908 us; speedup vs baseline: 1.6560x; 1.6560x over previous
//
#include <hip/hip_runtime.h>

#define Bq 2
#define Nq 1024
#define Cq 128
#define Eq 64
#define Kq 20
#define TI 8
#define BNK (Bq * Nq * Kq)
#define NEGF (-3.0e38f)

// DPP shuffles (VALU pipe, no LDS): quad_perm xor1/xor2, row_ror 4/8
#define DPP_F(x, ctrl) __int_as_float(__builtin_amdgcn_update_dpp( \
    __float_as_int(x), __float_as_int(x), (ctrl), 0xf, 0xf, false))
#define DPP_I(x, ctrl) __builtin_amdgcn_update_dpp((x), (x), (ctrl), 0xf, 0xf, false)
#define RL_F(x, l) __int_as_float(__builtin_amdgcn_readlane(__float_as_int(x), (l)))
#define RL_I(x, l) __builtin_amdgcn_readlane((x), (l))
#define QP_XOR1 0xB1   // quad_perm [1,0,3,2]
#define QP_XOR2 0x4E   // quad_perm [2,3,0,1]
#define ROR4    0x124  // row_ror:4
#define ROR8    0x128  // row_ror:8

// ---------------- Kernel A: projections + rdot (R1 shape: 1 row/block) ----------------
// grid = B*N, block = 128 (2 waves). Wave 0 -> Wl (xl row), wave 1 -> Wr (xrT col + rdot).
// 8 blocks/CU, 4 waves/SIMD; W stays L1-resident.
__global__ __launch_bounds__(128) void proj_kernel(
    const float* __restrict__ x, const float* __restrict__ Wl,
    const float* __restrict__ bl, const float* __restrict__ Wr,
    const float* __restrict__ br, const float* __restrict__ att,
    float* __restrict__ xl, float* __restrict__ xrT, float* __restrict__ rdot) {
  const int row = blockIdx.x;
  const int t = threadIdx.x;
  const int e = t & 63;
  const bool left = (t < 64);
  __shared__ float xs[Cq];
  xs[t] = x[(size_t)row * Cq + t];
  __syncthreads();
  const float* __restrict__ W = left ? Wl : Wr;
  float acc = 0.f;
#pragma unroll 8
  for (int c = 0; c < Cq; ++c) acc = fmaf(xs[c], W[c * Eq + e], acc);
  acc += left ? bl[e] : br[e];
  if (left) {
    xl[(size_t)row * Eq + e] = acc;
  } else {
    xrT[(size_t)e * (Bq * Nq) + row] = acc;
    float s = acc * att[e];                 // rdot[row] = sum_e xr[row][e]*att[e]
    s += DPP_F(s, QP_XOR1);
    s += DPP_F(s, QP_XOR2);
    s += DPP_F(s, ROR4);
    s += DPP_F(s, ROR8);
    const float sd = (RL_F(s, 0) + RL_F(s, 16)) + (RL_F(s, 32) + RL_F(s, 48));
    if (e == 0) rdot[row] = sd;
  }
}

// ---------------- Kernel B: scores (8 rows/block, 1024 threads) + DPP top-K ----------------
// Phase 1: thread = (rgroup of 2 rows: tid>>8) x (4 consecutive j: (tid&255)*4).
// 16 waves/CU = 4 waves/SIMD. Phase 2: waves 0..7 own rows 0..7 (DPP-only reduces).
__global__ __launch_bounds__(1024) void attn_kernel(
    const float* __restrict__ xl, const float* __restrict__ xrT,
    const float* __restrict__ rdot, const float* __restrict__ att,
    float* __restrict__ out) {
  const int gi0  = blockIdx.x * TI;
  const int b    = gi0 >> 10;
  const int tid  = threadIdx.x;
  const int lane = tid & 63;
  const int wave = tid >> 6;

  __shared__ float alpha[TI][Nq];   // 32 KB
  __shared__ float xls[TI][Eq];     // 2 KB

  if (tid < TI * Eq) xls[tid >> 6][tid & 63] = xl[(size_t)gi0 * Eq + tid];
  __syncthreads();

  // ---- phase 1: alphaS[r][j] = 1.5*rdot[j] + sum_d att[d]*|xl[r][d]+xr[j][d]| ----
  {
    const int jt = tid & 255;
    const int j0 = jt * 4;
    const int r0 = (tid >> 8) * 2;          // rows r0, r0+1
    const float4 rd4 = *(const float4*)&rdot[b * Nq + j0];
    float acc0[4], acc1[4];
    acc0[0] = 1.5f * rd4.x; acc0[1] = 1.5f * rd4.y;
    acc0[2] = 1.5f * rd4.z; acc0[3] = 1.5f * rd4.w;
    acc1[0] = acc0[0]; acc1[1] = acc0[1]; acc1[2] = acc0[2]; acc1[3] = acc0[3];

    const float* __restrict__ xrb = xrT + (size_t)b * Nq + j0;
#pragma unroll
    for (int ch = 0; ch < 16; ++ch) {
      const float4 av4 = *(const float4*)&att[ch * 4];            // uniform
      const float4 xla = *(const float4*)&xls[r0][ch * 4];        // LDS broadcast
      const float4 xlb = *(const float4*)&xls[r0 + 1][ch * 4];
      const float av[4]  = {av4.x, av4.y, av4.z, av4.w};
      const float la[4]  = {xla.x, xla.y, xla.z, xla.w};
      const float lb[4]  = {xlb.x, xlb.y, xlb.z, xlb.w};
#pragma unroll
      for (int dd = 0; dd < 4; ++dd) {
        const float4 xv4 = *(const float4*)&xrb[(size_t)(ch * 4 + dd) * (Bq * Nq)];
        const float xv[4] = {xv4.x, xv4.y, xv4.z, xv4.w};
        const float a = av[dd];
#pragma unroll
        for (int jj = 0; jj < 4; ++jj) {
          acc0[jj] = fmaf(fabsf(la[dd] + xv[jj]), a, acc0[jj]);
          acc1[jj] = fmaf(fabsf(lb[dd] + xv[jj]), a, acc1[jj]);
        }
      }
    }
    *(float4*)&alpha[r0][j0]     = make_float4(acc0[0], acc0[1], acc0[2], acc0[3]);
    *(float4*)&alpha[r0 + 1][j0] = make_float4(acc1[0], acc1[1], acc1[2], acc1[3]);
  }
  __syncthreads();

  // ---- phase 2: waves 0..7 = top-K of row `wave`, DPP-only reduces ----
  if (wave < TI) {
    float vals[16];
#pragma unroll
    for (int s = 0; s < 16; ++s) vals[s] = alpha[wave][lane + 64 * s];

    float lv = vals[0];
    int   pk = lane;                      // pk = (s<<6)|lane == j
#pragma unroll
    for (int s = 1; s < 16; ++s)
      if (vals[s] > lv) { lv = vals[s]; pk = (s << 6) | lane; }

    float m0 = 0.f, ssum = 0.f, myv = 0.f;
    int myi = 0;
#pragma unroll 1
    for (int round = 0; round < Kq; ++round) {
      float m = lv;
      m = fmaxf(m, DPP_F(m, QP_XOR1));
      m = fmaxf(m, DPP_F(m, QP_XOR2));
      m = fmaxf(m, DPP_F(m, ROR4));
      m = fmaxf(m, DPP_F(m, ROR8));
      const float bv = fmaxf(fmaxf(RL_F(m, 0), RL_F(m, 16)),
                             fmaxf(RL_F(m, 32), RL_F(m, 48)));
      int key = (lv == bv) ? pk : 0x7FFFFFFF;   // min-j tie-break (lax.top_k)
      key = min(key, DPP_I(key, QP_XOR1));
      key = min(key, DPP_I(key, QP_XOR2));
      key = min(key, DPP_I(key, ROR4));
      key = min(key, DPP_I(key, ROR8));
      const int jsel = min(min(RL_I(key, 0), RL_I(key, 16)),
                           min(RL_I(key, 32), RL_I(key, 48)));
      if (round == 0) m0 = bv;
      ssum += __expf(0.4f * (bv - m0));
      if (lane == round) { myv = bv; myi = jsel; }
      if (lane == (jsel & 63)) {          // owner knockout + rescan
        const int sk = jsel >> 6;
#pragma unroll
        for (int s = 0; s < 16; ++s)
          if (s == sk) vals[s] = NEGF;
        lv = vals[0]; pk = lane;
#pragma unroll
        for (int s = 1; s < 16; ++s)
          if (vals[s] > lv) { lv = vals[s]; pk = (s << 6) | lane; }
      }
    }

    if (lane < Kq) {
      const int gi = gi0 + wave;
      const float p = __expf(0.4f * (myv - m0)) / ssum;
      const int base = gi * Kq + lane;
      out[base]            = (float)gi;              // index_i
      out[BNK + base]      = (float)(b * Nq + myi);  // index_j
      out[2 * BNK + base]  = p;                      // attention
    }
  }
}

extern "C" void kernel_launch(void* const* d_in, const int* in_sizes, int n_in,
                              void* d_out, int out_size, void* d_ws, size_t ws_size,
                              hipStream_t stream) {
  const float* x   = (const float*)d_in[0];
  const float* Wl  = (const float*)d_in[1];
  const float* bl  = (const float*)d_in[2];
  const float* Wr  = (const float*)d_in[3];
  const float* br  = (const float*)d_in[4];
  const float* att = (const float*)d_in[5];
  float* out = (float*)d_out;

  float* xl   = (float*)d_ws;                    // [B*N, E]
  float* xrT  = xl + (size_t)Bq * Nq * Eq;       // [E, B*N]
  float* rdot = xrT + (size_t)Eq * Bq * Nq;      // [B*N]

  proj_kernel<<<Bq * Nq, 128, 0, stream>>>(x, Wl, bl, Wr, br, att, xl, xrT, rdot);
  attn_kernel<<<(Bq * Nq) / TI, 1024, 0, stream>>>(xl, xrT, rdot, att, out);
}